// Round 13
// baseline (214.366 us; speedup 1.0000x reference)
//
#include <hip/hip_runtime.h>

#define NDIM 64
#define WPAD 68
#define BINSHIFT 6
#define BINSZ 64           // nodes per bin
#define LCAP 3072          // per-bin edge cap (mean 2048)
#define STCAP (LCAP + 512) // sT capacity: LCAP + max align8 padding
#define EPT 8
#define PCHUNK (256 * EPT) // 2048 edges per partition chunk
#define MAXBINS 1024

typedef unsigned short ushort;

__device__ __forceinline__ ushort f2bf(float f) {
    unsigned u = __float_as_uint(f);
    return (ushort)((u + 0x7FFFu + ((u >> 16) & 1u)) >> 16);  // RNE
}
__device__ __forceinline__ float bflo(unsigned u) { return __uint_as_float(u << 16); }
__device__ __forceinline__ float bfhi(unsigned u) { return __uint_as_float(u & 0xFFFF0000u); }

// ---- Phase 1: Mb[n][d] = sigmoid(g)*e, bf16. reps>1 = attribution probe ----
__global__ __launch_bounds__(256) void node_msg_kernel(
    const float* __restrict__ x, const float* __restrict__ W,
    ushort* __restrict__ Mb, int n_nodes, int reps)
{
    __shared__ float sW[128 * WPAD];
    __shared__ float sx[4][4][64];

    for (int i = threadIdx.x; i < 128 * 64; i += 256)
        sW[(i >> 6) * WPAD + (i & 63)] = W[i];
    __syncthreads();

    const int wid  = threadIdx.x >> 6;
    const int lane = threadIdx.x & 63;
    const float4* __restrict__ wg4 = (const float4*)&sW[lane * WPAD];
    const float4* __restrict__ we4 = (const float4*)&sW[(lane + 64) * WPAD];

    for (int rep = 0; rep < reps; ++rep) {
        int n0 = (blockIdx.x * 4 + wid) * 4;
        int stride = gridDim.x * 16;
        for (; n0 < n_nodes; n0 += stride) {
            #pragma unroll
            for (int q = 0; q < 4; ++q) {
                int n = n0 + q;
                sx[wid][q][lane] = (n < n_nodes) ? x[(size_t)n * NDIM + lane] : 0.0f;
            }
            float g[4] = {0, 0, 0, 0}, e[4] = {0, 0, 0, 0};
            #pragma unroll
            for (int k4 = 0; k4 < 16; ++k4) {
                float4 a = wg4[k4];
                float4 b = we4[k4];
                #pragma unroll
                for (int q = 0; q < 4; ++q) {
                    float4 xk = *(const float4*)&sx[wid][q][k4 * 4];
                    g[q] = fmaf(xk.x, a.x, g[q]); g[q] = fmaf(xk.y, a.y, g[q]);
                    g[q] = fmaf(xk.z, a.z, g[q]); g[q] = fmaf(xk.w, a.w, g[q]);
                    e[q] = fmaf(xk.x, b.x, e[q]); e[q] = fmaf(xk.y, b.y, e[q]);
                    e[q] = fmaf(xk.z, b.z, e[q]); e[q] = fmaf(xk.w, b.w, e[q]);
                }
            }
            #pragma unroll
            for (int q = 0; q < 4; ++q) {
                int n = n0 + q;
                if (n < n_nodes)
                    Mb[(size_t)n * NDIM + lane] = f2bf(e[q] / (1.0f + __expf(-g[q])));
            }
            __syncthreads();  // sx reuse across n0 iterations
        }
    }
}

// ---- Partition: scatter packed (local_s<<16|tgt) into 64-node bins ----
__global__ __launch_bounds__(256) void partition_kernel(
    const int* __restrict__ src, const int* __restrict__ tgt,
    int* __restrict__ binCursor, unsigned* __restrict__ binned,
    int n_edges, int nbins)
{
    __shared__ int h[MAXBINS];
    __shared__ int base[MAXBINS];
    const int tid = threadIdx.x;

    long long cb = (long long)blockIdx.x * PCHUNK;
    long long cs = (long long)gridDim.x * PCHUNK;
    for (; cb < n_edges; cb += cs) {
        for (int i = tid; i < nbins; i += 256) h[i] = 0;
        __syncthreads();

        unsigned pk[EPT]; ushort ps[EPT]; short pb[EPT];
        #pragma unroll
        for (int r = 0; r < EPT; ++r) {
            long long e = cb + r * 256 + tid;
            pb[r] = -1;
            if (e < n_edges) {
                int s = src[e], t = tgt[e];
                int b = s >> BINSHIFT;
                pk[r] = ((unsigned)(s & (BINSZ - 1)) << 16) | (unsigned)t;
                ps[r] = (ushort)atomicAdd(&h[b], 1);
                pb[r] = (short)b;
            }
        }
        __syncthreads();
        for (int i = tid; i < nbins; i += 256) {
            int c = h[i];
            base[i] = c ? atomicAdd(&binCursor[i], c) : 0;
        }
        __syncthreads();
        #pragma unroll
        for (int r = 0; r < EPT; ++r) {
            if (pb[r] >= 0) {
                unsigned d = (unsigned)base[pb[r]] + ps[r];
                if (d < LCAP) binned[(size_t)pb[r] * LCAP + d] = pk[r];
            }
        }
        __syncthreads();
    }
}

// ---- CSR build + gather fused; 256 threads, ~20KB LDS ----
__global__ __launch_bounds__(256) void csr_gather_kernel(
    const unsigned* __restrict__ binned, const int* __restrict__ binCursor,
    const ushort* __restrict__ Mb, const float* __restrict__ x,
    float* __restrict__ out, int n_nodes)
{
    __shared__ unsigned sE[LCAP];      // 12 KB staged edges
    __shared__ ushort   sT[STCAP];     // 7 KB placed target ids
    __shared__ int sCnt[BINSZ];
    __shared__ int sOff[BINSZ];
    __shared__ int sCur[BINSZ];

    const int bin = blockIdx.x;
    const int tid = threadIdx.x;
    const int cnt = min(binCursor[bin], LCAP);
    const unsigned* __restrict__ be = &binned[(size_t)bin * LCAP];

    if (tid < BINSZ) sCnt[tid] = 0;
    __syncthreads();
    for (int i = tid; i < cnt; i += 256) {
        unsigned v = be[i];
        sE[i] = v;
        atomicAdd(&sCnt[v >> 16], 1);
    }
    __syncthreads();

    if (tid < 64) {  // wave 0: exclusive scan of align8(counts), 1 node/lane
        int c = (sCnt[tid] + 7) & ~7;
        int incl = c;
        #pragma unroll
        for (int d = 1; d < 64; d <<= 1) {
            int t = __shfl_up(incl, d);
            if (tid >= d) incl += t;
        }
        int excl = incl - c;
        sOff[tid] = excl;
        sCur[tid] = excl;
    }
    __syncthreads();

    for (int i = tid; i < cnt; i += 256) {
        unsigned p = sE[i];
        int pos = atomicAdd(&sCur[p >> 16], 1);
        if (pos < STCAP) sT[pos] = (ushort)(p & 0xFFFFu);
    }
    __syncthreads();

    // Gather from LDS CSR: 4 waves x 8 subgroups x 2 rounds = 64 nodes.
    const int wid  = tid >> 6;
    const int lane = tid & 63;
    const int sub  = lane >> 3;   // subgroup in wave
    const int sl   = lane & 7;    // dim octet
    #pragma unroll
    for (int r = 0; r < BINSZ / 32; ++r) {
        int ln = r * 32 + wid * 8 + sub;
        int n  = (bin << BINSHIFT) + ln;
        int c  = sCnt[ln];
        int off = sOff[ln];
        float acc[8] = {0, 0, 0, 0, 0, 0, 0, 0};
        for (int j = 0; j < c; j += 8) {
            uint4 nb = *(const uint4*)&sT[off + j];   // 8 ids, subgroup-uniform
            unsigned id[8] = { nb.x & 0xFFFFu, nb.x >> 16, nb.y & 0xFFFFu, nb.y >> 16,
                               nb.z & 0xFFFFu, nb.z >> 16, nb.w & 0xFFFFu, nb.w >> 16 };
            #pragma unroll
            for (int k = 0; k < 8; ++k) {
                if (j + k < c) {
                    uint4 v = *(const uint4*)&Mb[(size_t)id[k] * NDIM + sl * 8];
                    acc[0] += bflo(v.x); acc[1] += bfhi(v.x);
                    acc[2] += bflo(v.y); acc[3] += bfhi(v.y);
                    acc[4] += bflo(v.z); acc[5] += bfhi(v.z);
                    acc[6] += bflo(v.w); acc[7] += bfhi(v.w);
                }
            }
        }
        if (n < n_nodes) {
            size_t base = (size_t)n * NDIM + sl * 8;
            float4 x0 = *(const float4*)&x[base];
            float4 x1 = *(const float4*)&x[base + 4];
            float4 o0 = {x0.x + acc[0], x0.y + acc[1], x0.z + acc[2], x0.w + acc[3]};
            float4 o1 = {x1.x + acc[4], x1.y + acc[5], x1.z + acc[6], x1.w + acc[7]};
            *(float4*)&out[base]     = o0;
            *(float4*)&out[base + 4] = o1;
        }
    }
}

// ---------------- Fallback: atomic scatter ----------------
__global__ __launch_bounds__(256) void copy_out_kernel(
    const float* __restrict__ x, float* __restrict__ out, size_t n)
{
    size_t i = (size_t)blockIdx.x * 256 + threadIdx.x;
    size_t gs = (size_t)gridDim.x * 256;
    for (; i < n; i += gs) out[i] = x[i];
}

__global__ __launch_bounds__(256) void edge_scatter_kernel(
    const int* __restrict__ src, const int* __restrict__ tgt,
    const ushort* __restrict__ Mb, float* __restrict__ out, int n_edges)
{
    long long total = (long long)n_edges * 16;
    long long i0 = (long long)blockIdx.x * blockDim.x + threadIdx.x;
    long long gs = (long long)gridDim.x * blockDim.x;
    for (long long i = i0; i < total; i += gs) {
        int e = (int)(i >> 4);
        int q = (int)(i & 15);
        int s = src[e];
        int t = tgt[e];
        uint2 v = *(const uint2*)&Mb[(size_t)t * NDIM + q * 4];
        float* o = &out[(size_t)s * NDIM + q * 4];
        atomicAdd(o + 0, bflo(v.x));
        atomicAdd(o + 1, bfhi(v.x));
        atomicAdd(o + 2, bflo(v.y));
        atomicAdd(o + 3, bfhi(v.y));
    }
}

static inline size_t align16(size_t v) { return (v + 15) & ~(size_t)15; }

extern "C" void kernel_launch(void* const* d_in, const int* in_sizes, int n_in,
                              void* d_out, int out_size, void* d_ws, size_t ws_size,
                              hipStream_t stream)
{
    const float* x   = (const float*)d_in[0];
    const float* W   = (const float*)d_in[1];
    const int*   src = (const int*)d_in[2];
    const int*   tgt = (const int*)d_in[3];

    int n_nodes = in_sizes[0] / NDIM;
    int n_edges = in_sizes[2];
    float* out = (float*)d_out;

    int nbins = (n_nodes + BINSZ - 1) >> BINSHIFT;

    char* ws = (char*)d_ws;
    size_t off = 0;
    ushort* Mb = (ushort*)(ws + off);         off = align16(off + (size_t)n_nodes * NDIM * 2);
    int* binCursor = (int*)(ws + off);        off = align16(off + (size_t)nbins * 4);
    unsigned* binned = (unsigned*)(ws + off); off = align16(off + (size_t)nbins * LCAP * 4);
    size_t need = off + 1024;

    if (ws_size >= need && n_nodes <= 65536 && nbins <= MAXBINS) {
        hipMemsetAsync(binCursor, 0, (size_t)nbins * sizeof(int), stream);
        // ATTRIBUTION ROUND 2: unfused; msg body repeated 4x internally
        // (idempotent). dur - R10 ~= 3*M (+unfuse delta) => isolates msg cost.
        node_msg_kernel<<<512, 256, 0, stream>>>(x, W, Mb, n_nodes, 4);
        partition_kernel<<<256, 256, 0, stream>>>(
            src, tgt, binCursor, binned, n_edges, nbins);
        csr_gather_kernel<<<nbins, 256, 0, stream>>>(
            binned, binCursor, Mb, x, out, n_nodes);
    } else if (ws_size >= (size_t)n_nodes * NDIM * sizeof(ushort)) {
        node_msg_kernel<<<512, 256, 0, stream>>>(x, W, Mb, n_nodes, 1);
        copy_out_kernel<<<2048, 256, 0, stream>>>(x, out, (size_t)n_nodes * NDIM);
        long long total = (long long)n_edges * 16;
        edge_scatter_kernel<<<(int)((total + 255) / 256), 256, 0, stream>>>(
            src, tgt, Mb, out, n_edges);
    }
}

// Round 14
// 99.831 us; speedup vs baseline: 2.1473x; 2.1473x over previous
//
#include <hip/hip_runtime.h>

#define NDIM 64
#define BINSHIFT 6
#define BINSZ 64           // nodes per bin
#define LCAP 3072          // per-bin edge cap (mean 2048)
#define STCAP (LCAP + 512) // sT capacity: LCAP + max align8 padding
#define EPT 8
#define PCHUNK (256 * EPT) // 2048 edges per partition chunk
#define MAXBINS 1024

typedef unsigned short ushort;
typedef short bf8 __attribute__((ext_vector_type(8)));   // 8 bf16 (4 VGPRs)
typedef float f32x4 __attribute__((ext_vector_type(4))); // MFMA acc

__device__ __forceinline__ ushort f2bf(float f) {
    unsigned u = __float_as_uint(f);
    return (ushort)((u + 0x7FFFu + ((u >> 16) & 1u)) >> 16);  // RNE
}
__device__ __forceinline__ float bflo(unsigned u) { return __uint_as_float(u << 16); }
__device__ __forceinline__ float bfhi(unsigned u) { return __uint_as_float(u & 0xFFFF0000u); }

__device__ __forceinline__ bf8 pack8(float4 a, float4 b) {
    bf8 r;
    r[0] = (short)f2bf(a.x); r[1] = (short)f2bf(a.y);
    r[2] = (short)f2bf(a.z); r[3] = (short)f2bf(a.w);
    r[4] = (short)f2bf(b.x); r[5] = (short)f2bf(b.y);
    r[6] = (short)f2bf(b.z); r[7] = (short)f2bf(b.w);
    return r;
}

// ---- Phase 1 via MFMA: Mb[n][d] = sigmoid(C[n][d]) * C[n][d+64],
//      C = x @ W.T.  Zero LDS; W held as B-fragments in VGPRs.
//      Frag layouts (16x16x32 bf16): A: lane l -> x[n0+(l&15)][32h+8*(l>>4)+e]
//      B: lane l -> W[16t+(l&15)][32h+8*(l>>4)+e]   (B = W^T as KxN)
//      C/D (m89): col=lane&15, row=4*(lane>>4)+reg.
__global__ __launch_bounds__(256) void node_msg_mfma(
    const float* __restrict__ x, const float* __restrict__ W,
    ushort* __restrict__ Mb, int n_nodes)
{
    const int lane = threadIdx.x & 63;
    const int wid  = threadIdx.x >> 6;
    const int r16  = lane & 15;
    const int g4   = lane >> 4;

    // Preload all 16 W fragments (8 dim-tiles x 2 k-halves) into VGPRs.
    bf8 bfrag[8][2];
    #pragma unroll
    for (int t = 0; t < 8; ++t) {
        #pragma unroll
        for (int h = 0; h < 2; ++h) {
            const float* wp = &W[(size_t)(t * 16 + r16) * NDIM + h * 32 + g4 * 8];
            bfrag[t][h] = pack8(*(const float4*)wp, *(const float4*)(wp + 4));
        }
    }

    int ntiles = (n_nodes + 15) >> 4;
    int stride = gridDim.x * 4;
    for (int tile = blockIdx.x * 4 + wid; tile < ntiles; tile += stride) {
        int n0 = tile * 16;
        int arow = min(n0 + r16, n_nodes - 1);   // clamp for tail tile
        bf8 afrag[2];
        #pragma unroll
        for (int h = 0; h < 2; ++h) {
            const float* xp = &x[(size_t)arow * NDIM + h * 32 + g4 * 8];
            afrag[h] = pack8(*(const float4*)xp, *(const float4*)(xp + 4));
        }
        f32x4 acc[8];
        #pragma unroll
        for (int t = 0; t < 8; ++t) acc[t] = (f32x4){0.f, 0.f, 0.f, 0.f};
        #pragma unroll
        for (int h = 0; h < 2; ++h) {
            #pragma unroll
            for (int t = 0; t < 8; ++t)
                acc[t] = __builtin_amdgcn_mfma_f32_16x16x32_bf16(
                    afrag[h], bfrag[t][h], acc[t], 0, 0, 0);
        }
        // Epilogue: lane covers node n = n0+4*g4+r, dim d = 16t+r16 (t<4).
        #pragma unroll
        for (int r = 0; r < 4; ++r) {
            int n = n0 + 4 * g4 + r;
            if (n < n_nodes) {
                #pragma unroll
                for (int t = 0; t < 4; ++t) {
                    float g = acc[t][r];
                    float e = acc[t + 4][r];
                    Mb[(size_t)n * NDIM + t * 16 + r16] =
                        f2bf(e / (1.0f + __expf(-g)));
                }
            }
        }
    }
}

// ---- Partition: scatter packed (local_s<<16|tgt) into 64-node bins ----
__global__ __launch_bounds__(256) void partition_kernel(
    const int* __restrict__ src, const int* __restrict__ tgt,
    int* __restrict__ binCursor, unsigned* __restrict__ binned,
    int n_edges, int nbins)
{
    __shared__ int h[MAXBINS];
    __shared__ int base[MAXBINS];
    const int tid = threadIdx.x;

    long long cb = (long long)blockIdx.x * PCHUNK;
    long long cs = (long long)gridDim.x * PCHUNK;
    for (; cb < n_edges; cb += cs) {
        for (int i = tid; i < nbins; i += 256) h[i] = 0;
        __syncthreads();

        unsigned pk[EPT]; ushort ps[EPT]; short pb[EPT];
        #pragma unroll
        for (int r = 0; r < EPT; ++r) {
            long long e = cb + r * 256 + tid;
            pb[r] = -1;
            if (e < n_edges) {
                int s = src[e], t = tgt[e];
                int b = s >> BINSHIFT;
                pk[r] = ((unsigned)(s & (BINSZ - 1)) << 16) | (unsigned)t;
                ps[r] = (ushort)atomicAdd(&h[b], 1);
                pb[r] = (short)b;
            }
        }
        __syncthreads();
        for (int i = tid; i < nbins; i += 256) {
            int c = h[i];
            base[i] = c ? atomicAdd(&binCursor[i], c) : 0;
        }
        __syncthreads();
        #pragma unroll
        for (int r = 0; r < EPT; ++r) {
            if (pb[r] >= 0) {
                unsigned d = (unsigned)base[pb[r]] + ps[r];
                if (d < LCAP) binned[(size_t)pb[r] * LCAP + d] = pk[r];
            }
        }
        __syncthreads();
    }
}

// ---- CSR build + gather fused; 256 threads, ~20KB LDS ----
__global__ __launch_bounds__(256) void csr_gather_kernel(
    const unsigned* __restrict__ binned, const int* __restrict__ binCursor,
    const ushort* __restrict__ Mb, const float* __restrict__ x,
    float* __restrict__ out, int n_nodes)
{
    __shared__ unsigned sE[LCAP];
    __shared__ ushort   sT[STCAP];
    __shared__ int sCnt[BINSZ];
    __shared__ int sOff[BINSZ];
    __shared__ int sCur[BINSZ];

    const int bin = blockIdx.x;
    const int tid = threadIdx.x;
    const int cnt = min(binCursor[bin], LCAP);
    const unsigned* __restrict__ be = &binned[(size_t)bin * LCAP];

    if (tid < BINSZ) sCnt[tid] = 0;
    __syncthreads();
    for (int i = tid; i < cnt; i += 256) {
        unsigned v = be[i];
        sE[i] = v;
        atomicAdd(&sCnt[v >> 16], 1);
    }
    __syncthreads();

    if (tid < 64) {
        int c = (sCnt[tid] + 7) & ~7;
        int incl = c;
        #pragma unroll
        for (int d = 1; d < 64; d <<= 1) {
            int t = __shfl_up(incl, d);
            if (tid >= d) incl += t;
        }
        int excl = incl - c;
        sOff[tid] = excl;
        sCur[tid] = excl;
    }
    __syncthreads();

    for (int i = tid; i < cnt; i += 256) {
        unsigned p = sE[i];
        int pos = atomicAdd(&sCur[p >> 16], 1);
        if (pos < STCAP) sT[pos] = (ushort)(p & 0xFFFFu);
    }
    __syncthreads();

    const int wid  = tid >> 6;
    const int lane = tid & 63;
    const int sub  = lane >> 3;
    const int sl   = lane & 7;
    #pragma unroll
    for (int r = 0; r < BINSZ / 32; ++r) {
        int ln = r * 32 + wid * 8 + sub;
        int n  = (bin << BINSHIFT) + ln;
        int c  = sCnt[ln];
        int off = sOff[ln];
        float acc[8] = {0, 0, 0, 0, 0, 0, 0, 0};
        for (int j = 0; j < c; j += 8) {
            uint4 nb = *(const uint4*)&sT[off + j];
            unsigned id[8] = { nb.x & 0xFFFFu, nb.x >> 16, nb.y & 0xFFFFu, nb.y >> 16,
                               nb.z & 0xFFFFu, nb.z >> 16, nb.w & 0xFFFFu, nb.w >> 16 };
            #pragma unroll
            for (int k = 0; k < 8; ++k) {
                if (j + k < c) {
                    uint4 v = *(const uint4*)&Mb[(size_t)id[k] * NDIM + sl * 8];
                    acc[0] += bflo(v.x); acc[1] += bfhi(v.x);
                    acc[2] += bflo(v.y); acc[3] += bfhi(v.y);
                    acc[4] += bflo(v.z); acc[5] += bfhi(v.z);
                    acc[6] += bflo(v.w); acc[7] += bfhi(v.w);
                }
            }
        }
        if (n < n_nodes) {
            size_t base = (size_t)n * NDIM + sl * 8;
            float4 x0 = *(const float4*)&x[base];
            float4 x1 = *(const float4*)&x[base + 4];
            float4 o0 = {x0.x + acc[0], x0.y + acc[1], x0.z + acc[2], x0.w + acc[3]};
            float4 o1 = {x1.x + acc[4], x1.y + acc[5], x1.z + acc[6], x1.w + acc[7]};
            *(float4*)&out[base]     = o0;
            *(float4*)&out[base + 4] = o1;
        }
    }
}

// ---------------- Fallback: atomic scatter ----------------
__global__ __launch_bounds__(256) void copy_out_kernel(
    const float* __restrict__ x, float* __restrict__ out, size_t n)
{
    size_t i = (size_t)blockIdx.x * 256 + threadIdx.x;
    size_t gs = (size_t)gridDim.x * 256;
    for (; i < n; i += gs) out[i] = x[i];
}

__global__ __launch_bounds__(256) void edge_scatter_kernel(
    const int* __restrict__ src, const int* __restrict__ tgt,
    const ushort* __restrict__ Mb, float* __restrict__ out, int n_edges)
{
    long long total = (long long)n_edges * 16;
    long long i0 = (long long)blockIdx.x * blockDim.x + threadIdx.x;
    long long gs = (long long)gridDim.x * blockDim.x;
    for (long long i = i0; i < total; i += gs) {
        int e = (int)(i >> 4);
        int q = (int)(i & 15);
        int s = src[e];
        int t = tgt[e];
        uint2 v = *(const uint2*)&Mb[(size_t)t * NDIM + q * 4];
        float* o = &out[(size_t)s * NDIM + q * 4];
        atomicAdd(o + 0, bflo(v.x));
        atomicAdd(o + 1, bfhi(v.x));
        atomicAdd(o + 2, bflo(v.y));
        atomicAdd(o + 3, bfhi(v.y));
    }
}

static inline size_t align16(size_t v) { return (v + 15) & ~(size_t)15; }

extern "C" void kernel_launch(void* const* d_in, const int* in_sizes, int n_in,
                              void* d_out, int out_size, void* d_ws, size_t ws_size,
                              hipStream_t stream)
{
    const float* x   = (const float*)d_in[0];
    const float* W   = (const float*)d_in[1];
    const int*   src = (const int*)d_in[2];
    const int*   tgt = (const int*)d_in[3];

    int n_nodes = in_sizes[0] / NDIM;
    int n_edges = in_sizes[2];
    float* out = (float*)d_out;

    int nbins = (n_nodes + BINSZ - 1) >> BINSHIFT;

    char* ws = (char*)d_ws;
    size_t off = 0;
    ushort* Mb = (ushort*)(ws + off);         off = align16(off + (size_t)n_nodes * NDIM * 2);
    int* binCursor = (int*)(ws + off);        off = align16(off + (size_t)nbins * 4);
    unsigned* binned = (unsigned*)(ws + off); off = align16(off + (size_t)nbins * LCAP * 4);
    size_t need = off + 1024;

    if (ws_size >= need && n_nodes <= 65536 && nbins <= MAXBINS) {
        hipMemsetAsync(binCursor, 0, (size_t)nbins * sizeof(int), stream);
        node_msg_mfma<<<512, 256, 0, stream>>>(x, W, Mb, n_nodes);
        partition_kernel<<<256, 256, 0, stream>>>(
            src, tgt, binCursor, binned, n_edges, nbins);
        csr_gather_kernel<<<nbins, 256, 0, stream>>>(
            binned, binCursor, Mb, x, out, n_nodes);
    } else if (ws_size >= (size_t)n_nodes * NDIM * sizeof(ushort)) {
        node_msg_mfma<<<512, 256, 0, stream>>>(x, W, Mb, n_nodes);
        copy_out_kernel<<<2048, 256, 0, stream>>>(x, out, (size_t)n_nodes * NDIM);
        long long total = (long long)n_edges * 16;
        edge_scatter_kernel<<<(int)((total + 255) / 256), 256, 0, stream>>>(
            src, tgt, Mb, out, n_edges);
    }
}